// Round 10
// baseline (921.290 us; speedup 1.0000x reference)
//
#include <hip/hip_runtime.h>
#include <stdint.h>

#define Nn 4096
#define Dd 512
#define Ee 65536
#define HOPS 10
#define TPB 512
#define RPT (Nn / TPB)  // 8 rows per thread
#define CT8 8           // packed bf16 columns per block (8 x bf16 = 16B LDS entry)
#define WCAP 64         // ELL slot capacity (max in-degree+1; Poisson(16) max ~38)
#define KEXT 1536       // hi/lo-split extension K: [Phi|Phi|Plo] x [Yhi|Ylo|Yhi]
#define YC 640          // padded col count of Y = [X(512)|u|1|pad...]
#define XK 8192         // xb row length: [hi(4096) | lo(4096)]
#define NTMM 88         // k_mm2 K-tiles: 64 (Mb, K=4096) + 24 (ext, K=1536)

typedef short bf16x8 __attribute__((ext_vector_type(8)));
typedef float f32x4 __attribute__((ext_vector_type(4)));

// ---------------- helpers ----------------
__device__ __forceinline__ unsigned short bf16r(float x) {  // RNE fp32->bf16
  unsigned int b = __float_as_uint(x);
  return (unsigned short)((b + 0x7FFFu + ((b >> 16) & 1u)) >> 16);
}
__device__ __forceinline__ unsigned int pkbf(float lo, float hi) {  // 2 cols -> 1 uint
  return (unsigned int)bf16r(lo) | ((unsigned int)bf16r(hi) << 16);
}
__device__ __forceinline__ float ubf(unsigned short h) {
  return __uint_as_float(((unsigned int)h) << 16);
}
__device__ __forceinline__ void gld16(const unsigned short* g, unsigned short* lds) {
  __builtin_amdgcn_global_load_lds(
      (const __attribute__((address_space(1))) unsigned int*)g,
      (__attribute__((address_space(3))) unsigned int*)lds, 16, 0, 0);
}

// Mb is stored chunk-tiled: Mb_t[(c/8)*Nn*8 + row*8 + (c&7)] -> full-line coalesced
// writes in k_appnp (kills RFO/write-amp) and clean 16B staging reads (chunk-aligned).

// ---------------- sq[i] = sum_d w_d * x[i,d]^2 ----------------
__global__ __launch_bounds__(256) void k_sq(const float* __restrict__ x,
                                            const float* __restrict__ w,
                                            float* __restrict__ sq) {
  int row = blockIdx.x;
  int tid = threadIdx.x;
  const float* xr = x + (size_t)row * Dd;
  float partial = 0.f;
  for (int d = tid; d < Dd; d += 256) {
    float xv = xr[d];
    partial += xv * xv * w[d];
  }
  for (int off = 32; off >= 1; off >>= 1) partial += __shfl_down(partial, off, 64);
  __shared__ float red[4];
  int wv = tid >> 6, ln = tid & 63;
  if (ln == 0) red[wv] = partial;
  __syncthreads();
  if (tid == 0) sq[row] = red[0] + red[1] + red[2] + red[3];
}

// ---------------- degree counting ----------------
__global__ void k_count(const int* __restrict__ src, const int* __restrict__ dst,
                        int* __restrict__ degi, int* __restrict__ degrow) {
  int e = blockIdx.x * blockDim.x + threadIdx.x;
  if (e < Ee) {
    atomicAdd(&degi[dst[e]], 1);
    atomicAdd(&degrow[src[e]], 1);
  }
}

// ---------------- dis = (deg_in+1)^-0.5 ; d2 = 1/(deg_row+1) ----------------
__global__ void k_dis(const int* __restrict__ degi, const int* __restrict__ degrow,
                      float* __restrict__ dis, float* __restrict__ d2) {
  int i = blockIdx.x * 256 + threadIdx.x;
  dis[i] = rsqrtf((float)(degi[i] + 1));
  d2[i] = 1.0f / ((float)degrow[i] + 1.0f);
}

// ---------------- histogram of (deg_in+1) + exclusive prefix -> binbase ----------------
__global__ void k_hist(const int* __restrict__ degi, int* __restrict__ binbase) {
  __shared__ int h[WCAP + 1];
  int t = threadIdx.x;
  if (t <= WCAP) h[t] = 0;
  __syncthreads();
  for (int i = t; i < Nn; i += 256) {
    int d = degi[i] + 1;
    if (d > WCAP) d = WCAP;
    atomicAdd(&h[d], 1);
  }
  __syncthreads();
  if (t == 0) {
    int run = 0;
    for (int b = 0; b <= WCAP; b++) { int c = h[b]; binbase[b] = run; run += c; }
  }
}

// ---------------- counting-sort scatter: perm (sorted pos -> row), rnk (row -> pos) ----------------
__global__ void k_scatter(const int* __restrict__ degi, const int* __restrict__ binbase,
                          int* __restrict__ bincnt, int* __restrict__ perm,
                          int* __restrict__ rnk) {
  int i = blockIdx.x * 256 + threadIdx.x;
  int d = degi[i] + 1;
  if (d > WCAP) d = WCAP;
  int pos = binbase[d] + atomicAdd(&bincnt[d], 1);
  perm[pos] = i;
  rnk[i] = pos;
}

// ---------------- per-(wave,chain) slot bounds ----------------
__global__ void k_wsub(const int* __restrict__ degi, const int* __restrict__ perm,
                       int* __restrict__ wsub) {
  int t = threadIdx.x;
  int d = degi[perm[t * 64 + 63]] + 1;
  wsub[t] = d > WCAP ? WCAP : d;
}

// ---------------- ELL fill (slot-major, sorted-position indexed) ----------------
__global__ void k_fill_ell(const int* __restrict__ src, const int* __restrict__ dst,
                           const float* __restrict__ dis, const int* __restrict__ rnk,
                           int* __restrict__ slot, int2* __restrict__ ell) {
  int i = blockIdx.x * blockDim.x + threadIdx.x;
  if (i < Ee) {
    int s = src[i], d = dst[i];
    int p = atomicAdd(&slot[d], 1);
    if (p < WCAP) ell[(size_t)p * Nn + rnk[d]] = make_int2(s, __float_as_int(dis[s] * dis[d]));
  } else if (i < Ee + Nn) {
    int v = i - Ee;
    int p = atomicAdd(&slot[v], 1);
    if (p < WCAP) ell[(size_t)p * Nn + rnk[v]] = make_int2(v, __float_as_int(dis[v] * dis[v]));
  }
}

// ---------------- xb[c][k] = bf16 hi/lo of X^T: rows c = feature cols, k = nodes ----------------
__global__ __launch_bounds__(256) void k_xpose(const float* __restrict__ x,
                                               unsigned short* __restrict__ xb) {
  __shared__ float tile[32][33];
  int cx = blockIdx.x, rx = blockIdx.y;
  int t = threadIdx.x, txc = t & 31, tyc = t >> 5;
#pragma unroll
  for (int i = 0; i < 4; i++) {
    int a = tyc + i * 8;
    tile[a][txc] = x[(size_t)(rx * 32 + a) * Dd + cx * 32 + txc];
  }
  __syncthreads();
#pragma unroll
  for (int i = 0; i < 4; i++) {
    int a = tyc + i * 8;
    int c = cx * 32 + a;
    float v = tile[txc][a];
    unsigned short hi = bf16r(v);
    xb[(size_t)c * XK + rx * 32 + txc] = hi;
    xb[(size_t)c * XK + Nn + rx * 32 + txc] = bf16r(v - ubf(hi));
  }
}

// ---------------- xb tail rows: u (=sq) at c=512, ones at c=513 ----------------
__global__ void k_tail(const float* __restrict__ sq, unsigned short* __restrict__ xb) {
  int r = blockIdx.x * 256 + threadIdx.x;
  float v = sq[r];
  unsigned short hi = bf16r(v);
  xb[(size_t)512 * XK + r] = hi;
  xb[(size_t)512 * XK + Nn + r] = bf16r(v - ubf(hi));
  xb[(size_t)513 * XK + r] = bf16r(1.0f);
  xb[(size_t)513 * XK + Nn + r] = 0;
}

// ---------------- fused 10-hop APPNP(I) -> Mb (chunk-tiled bf16); h packed bf16x8 in LDS ----------------
__global__ __launch_bounds__(TPB, 4) void k_appnp(unsigned short* __restrict__ mb,
                                                  const int2* __restrict__ ell,
                                                  const int* __restrict__ perm,
                                                  const int* __restrict__ wsub) {
  extern __shared__ uint4 h4u[];  // Nn entries = 64 KB (8 bf16 cols packed)
  int j0 = blockIdx.x * CT8;
  int tid = threadIdx.x;
  int wv = tid >> 6, ln = tid & 63;
  int qb = wv * 512 + ln;

  // init h = identity columns j0..j0+7 (bf16(1.0) = 0x3F80 in the matching half-word)
#pragma unroll
  for (int rr = 0; rr < RPT; rr++) {
    int r = tid + rr * TPB;
    uint4 v = make_uint4(0u, 0u, 0u, 0u);
    int c = r - j0;
    if (c >= 0 && c < 8) {
      unsigned int one = (c & 1) ? 0x3F800000u : 0x00003F80u;
      if ((c >> 1) == 0) v.x = one;
      else if ((c >> 1) == 1) v.y = one;
      else if ((c >> 1) == 2) v.z = one;
      else v.w = one;
    }
    h4u[r] = v;
  }

  int ws[RPT];
#pragma unroll
  for (int rr = 0; rr < RPT; rr++)
    ws[rr] = __builtin_amdgcn_readfirstlane(wsub[wv * 8 + rr]);
  const int Wv = ws[RPT - 1];

  int rp[RPT], x0c[RPT];
#pragma unroll
  for (int rr = 0; rr < RPT; rr++) {
    rp[rr] = perm[qb + rr * 64];
    int c = rp[rr] - j0;
    x0c[rr] = (c >= 0 && c < 8) ? c : -1;
  }
  __syncthreads();

  for (int it = 0; it < HOPS; it++) {
    int2 cur[RPT];
#pragma unroll
    for (int rr = 0; rr < RPT; rr++) cur[rr] = ell[qb + rr * 64];
    float acc[RPT][8];
#pragma unroll
    for (int rr = 0; rr < RPT; rr++)
#pragma unroll
      for (int c = 0; c < 8; c++) acc[rr][c] = (x0c[rr] == c) ? 1.0f : 0.0f;
    for (int s = 0; s < Wv; s++) {
      int sn = s + 1;
      int2 nxt[RPT];
#pragma unroll
      for (int rr = 0; rr < RPT; rr++)
        if (sn < ws[rr]) nxt[rr] = ell[(size_t)sn * Nn + qb + rr * 64];
#pragma unroll
      for (int rr = 0; rr < RPT; rr++)
        if (s < ws[rr]) {
          float vv = __int_as_float(cur[rr].y);
          uint4 hu = h4u[cur[rr].x];
          acc[rr][0] = fmaf(vv, __uint_as_float(hu.x << 16), acc[rr][0]);
          acc[rr][1] = fmaf(vv, __uint_as_float(hu.x & 0xFFFF0000u), acc[rr][1]);
          acc[rr][2] = fmaf(vv, __uint_as_float(hu.y << 16), acc[rr][2]);
          acc[rr][3] = fmaf(vv, __uint_as_float(hu.y & 0xFFFF0000u), acc[rr][3]);
          acc[rr][4] = fmaf(vv, __uint_as_float(hu.z << 16), acc[rr][4]);
          acc[rr][5] = fmaf(vv, __uint_as_float(hu.z & 0xFFFF0000u), acc[rr][5]);
          acc[rr][6] = fmaf(vv, __uint_as_float(hu.w << 16), acc[rr][6]);
          acc[rr][7] = fmaf(vv, __uint_as_float(hu.w & 0xFFFF0000u), acc[rr][7]);
        }
#pragma unroll
      for (int rr = 0; rr < RPT; rr++)
        if (sn < ws[rr]) cur[rr] = nxt[rr];
    }
    __syncthreads();
#pragma unroll
    for (int rr = 0; rr < RPT; rr++) {
      uint4 v;
      v.x = pkbf(0.5f * acc[rr][0], 0.5f * acc[rr][1]);
      v.y = pkbf(0.5f * acc[rr][2], 0.5f * acc[rr][3]);
      v.z = pkbf(0.5f * acc[rr][4], 0.5f * acc[rr][5]);
      v.w = pkbf(0.5f * acc[rr][6], 0.5f * acc[rr][7]);
      h4u[rp[rr]] = v;
    }
    __syncthreads();
  }

  // tiled write: chunk = blockIdx.x; 16B per thread, fully contiguous full lines
#pragma unroll
  for (int rr = 0; rr < RPT; rr++) {
    int r = tid + rr * TPB;
    *(uint4*)&mb[(size_t)blockIdx.x * Nn * 8 + (size_t)r * 8] = h4u[r];
  }
}

// ---------------- 128^2 MFMA tile step: A = Mb (chunk-tiled), B = xb (row-major) -------------
__device__ __forceinline__ void mm_step(const unsigned short* __restrict__ Mb,
                                        const unsigned short* __restrict__ Bp, int ldb,
                                        unsigned short* As, unsigned short* Bs,
                                        int i0, int j0, int k0, int l, int w, int wr,
                                        int wc, f32x4 acc[4][4]) {
  int rsub = w * 8 + (l >> 3);              // row within 32-row round
  int scg = ((l & 7) ^ (l >> 3)) * 8;       // pre-swizzled source chunk offset (ushorts)
#pragma unroll
  for (int r = 0; r < 4; r++) {
    int row = r * 32 + rsub;
    gld16(Mb + (size_t)(k0 + scg) * Nn + (size_t)(i0 + row) * 8, As + (r * 32 + w * 8) * 64);
    gld16(Bp + (size_t)(j0 + row) * ldb + k0 + scg, Bs + (r * 32 + w * 8) * 64);
  }
  __syncthreads();
#pragma unroll
  for (int q = 0; q < 2; q++) {
    bf16x8 af[4], bg[4];
#pragma unroll
    for (int m = 0; m < 4; m++) {
      int ar = wr * 64 + m * 16 + (l & 15);
      af[m] = *(const bf16x8*)(As + ar * 64 + ((((l >> 4) + 4 * q) ^ (ar & 7)) * 8));
      int br = wc * 64 + m * 16 + (l & 15);
      bg[m] = *(const bf16x8*)(Bs + br * 64 + ((((l >> 4) + 4 * q) ^ (br & 7)) * 8));
    }
#pragma unroll
    for (int m = 0; m < 4; m++)
#pragma unroll
      for (int n = 0; n < 4; n++)
        acc[m][n] = __builtin_amdgcn_mfma_f32_16x16x32_bf16(af[m], bg[n], acc[m][n], 0, 0, 0);
  }
  __syncthreads();
}

// ---------------- Y = Mb * xb^T (K = 4096 hi + 4096 lo); epilogue -> aext/bext/mu/m1 ----------------
__global__ __launch_bounds__(256) void k_ymm(const unsigned short* __restrict__ Mb,
                                             const unsigned short* __restrict__ xb,
                                             const float* __restrict__ wp,
                                             unsigned short* __restrict__ aext,
                                             unsigned short* __restrict__ bext,
                                             float* __restrict__ mu,
                                             float* __restrict__ m1) {
  __shared__ unsigned short As[128 * 64];
  __shared__ unsigned short Bs[128 * 64];
  int i0 = blockIdx.y * 128, j0 = blockIdx.x * 128;
  int tid = threadIdx.x, l = tid & 63, w = tid >> 6;
  int wr = w >> 1, wc = w & 1;
  f32x4 acc[4][4];
#pragma unroll
  for (int m = 0; m < 4; m++)
#pragma unroll
    for (int n = 0; n < 4; n++) acc[m][n] = (f32x4){0.f, 0.f, 0.f, 0.f};

  for (int k0 = 0; k0 < Nn; k0 += 64)
    mm_step(Mb, xb, XK, As, Bs, i0, j0, k0, l, w, wr, wc, acc);
  for (int k0 = 0; k0 < Nn; k0 += 64)
    mm_step(Mb, xb + Nn, XK, As, Bs, i0, j0, k0, l, w, wr, wc, acc);

#pragma unroll
  for (int m = 0; m < 4; m++) {
#pragma unroll
    for (int n = 0; n < 4; n++) {
#pragma unroll
      for (int q = 0; q < 4; q++) {
        int gi = i0 + wr * 64 + m * 16 + ((l >> 4) << 2) + q;
        int gj = j0 + wc * 64 + n * 16 + (l & 15);
        float y = acc[m][n][q];
        if (gj < 512) {
          unsigned short yhi = bf16r(y);
          unsigned short ylo = bf16r(y - ubf(yhi));
          float p = -2.f * wp[gj] * y;
          unsigned short phi = bf16r(p);
          unsigned short plo = bf16r(p - ubf(phi));
          bext[(size_t)gi * KEXT + gj] = yhi;
          bext[(size_t)gi * KEXT + 512 + gj] = ylo;
          bext[(size_t)gi * KEXT + 1024 + gj] = yhi;
          aext[(size_t)gi * KEXT + gj] = phi;
          aext[(size_t)gi * KEXT + 512 + gj] = phi;
          aext[(size_t)gi * KEXT + 1024 + gj] = plo;
        } else if (gj == 512) {
          mu[gi] = y;
        } else if (gj == 513) {
          m1[gi] = y;
        }
      }
    }
  }
}

// ---------------- 8-wave 256^2 GEMM: out = Mb Mb^T + Aext Bext^T + rank2, diag*d2 ----------
// All 8 staging loads for tile kt+1 issued at phase 0 of tile kt; single vmcnt(0) at
// phase 3 -> >=3-phase issue-to-drain distance (was 1). Raw s_barrier, setprio on MFMA.
__global__ __launch_bounds__(512, 2) void k_mm2(const unsigned short* __restrict__ Mb,
                                                const unsigned short* __restrict__ Aext,
                                                const unsigned short* __restrict__ Bext,
                                                const float* __restrict__ mu,
                                                const float* __restrict__ m1,
                                                const float* __restrict__ d2,
                                                float* __restrict__ out) {
  extern __shared__ unsigned short sh[];  // [A0|A1|B0|B1], each 256*64 ushort = 32 KB
  int lid = blockIdx.x;
  int swz = (lid & 7) * 32 + (lid >> 3);  // 256 % 8 == 0 -> bijective XCD swizzle
  int i0 = (swz >> 4) * 256, j0 = (swz & 15) * 256;
  int tid = threadIdx.x, l = tid & 63, w = tid >> 6;
  int wr = w >> 2, wc = w & 3;
  int rsub = l >> 3;
  int scg = ((l & 7) ^ (l >> 3)) * 8;          // pre-swizzled source chunk (ushorts)
  int aRowBase = wr * 128 + wc * 32;           // wave's A staging rows
  int bRowBase = (wc >> 1) * 128 + (wr * 2 + (wc & 1)) * 32;  // wave's B staging rows

  f32x4 acc[8][4];
#pragma unroll
  for (int m = 0; m < 8; m++)
#pragma unroll
    for (int n = 0; n < 4; n++) acc[m][n] = (f32x4){0.f, 0.f, 0.f, 0.f};

  auto STG = [&](int g, int t, int b) {  // g 0-3: B stage ; g 4-7: A stage
    if (t < 64) {  // Mb segment: chunk-tiled addressing
      int kk = t * 64;
      if (g < 4) {
        int r = bRowBase + g * 8;
        gld16(Mb + (size_t)(kk + scg) * Nn + (size_t)(j0 + r + rsub) * 8,
              sh + 32768 + b * 16384 + r * 64);
      } else {
        int r = aRowBase + (g - 4) * 8;
        gld16(Mb + (size_t)(kk + scg) * Nn + (size_t)(i0 + r + rsub) * 8,
              sh + b * 16384 + r * 64);
      }
    } else {  // ext segment: row-major
      int kk = (t - 64) * 64;
      if (g < 4) {
        int r = bRowBase + g * 8;
        gld16(Bext + (size_t)(j0 + r + rsub) * KEXT + kk + scg, sh + 32768 + b * 16384 + r * 64);
      } else {
        int r = aRowBase + (g - 4) * 8;
        gld16(Aext + (size_t)(i0 + r + rsub) * KEXT + kk + scg, sh + b * 16384 + r * 64);
      }
    }
  };

  // prologue: stage tile 0 into buf 0, drain, barrier
#pragma unroll
  for (int g = 0; g < 8; g++) STG(g, 0, 0);
  asm volatile("s_waitcnt vmcnt(0)" ::: "memory");
  __builtin_amdgcn_s_barrier();

  for (int kt = 0; kt < NTMM; kt++) {
    int cur = kt & 1, nxtb = cur ^ 1;
    const unsigned short* Ac = sh + cur * 16384;
    const unsigned short* Bc = sh + 32768 + cur * 16384;
    bool pre = (kt + 1 < NTMM);
#pragma unroll
    for (int p = 0; p < 4; p++) {
      const int mh = p >> 1, nh = p & 1;
      bf16x8 af[4][2], bg[2][2];
#pragma unroll
      for (int m4 = 0; m4 < 4; m4++) {
        int ar = wr * 128 + (mh * 4 + m4) * 16 + (l & 15);
#pragma unroll
        for (int ks = 0; ks < 2; ks++) {
          int c = ks * 4 + (l >> 4);
          af[m4][ks] = *(const bf16x8*)(Ac + ar * 64 + ((c ^ (ar & 7)) * 8));
        }
      }
#pragma unroll
      for (int n2 = 0; n2 < 2; n2++) {
        int br = wc * 64 + (nh * 2 + n2) * 16 + (l & 15);
#pragma unroll
        for (int ks = 0; ks < 2; ks++) {
          int c = ks * 4 + (l >> 4);
          bg[n2][ks] = *(const bf16x8*)(Bc + br * 64 + ((c ^ (br & 7)) * 8));
        }
      }
      if (pre && p == 0) {
#pragma unroll
        for (int g = 0; g < 8; g++) STG(g, kt + 1, nxtb);
      }
      if (p == 3) asm volatile("s_waitcnt vmcnt(0)" ::: "memory");
      __builtin_amdgcn_s_barrier();
      __builtin_amdgcn_s_setprio(1);
#pragma unroll
      for (int m4 = 0; m4 < 4; m4++)
#pragma unroll
        for (int n2 = 0; n2 < 2; n2++)
#pragma unroll
          for (int ks = 0; ks < 2; ks++)
            acc[mh * 4 + m4][nh * 2 + n2] = __builtin_amdgcn_mfma_f32_16x16x32_bf16(
                af[m4][ks], bg[n2][ks], acc[mh * 4 + m4][nh * 2 + n2], 0, 0, 0);
      __builtin_amdgcn_s_setprio(0);
      __builtin_amdgcn_s_barrier();
    }
  }

#pragma unroll
  for (int m = 0; m < 8; m++) {
#pragma unroll
    for (int n = 0; n < 4; n++) {
#pragma unroll
      for (int q = 0; q < 4; q++) {
        int gi = i0 + wr * 128 + m * 16 + ((l >> 4) << 2) + q;
        int gj = j0 + wc * 64 + n * 16 + (l & 15);
        float v = acc[m][n][q] + mu[gi] * m1[gj] + m1[gi] * mu[gj];
        if (gi == gj) v *= d2[gi];
        out[(size_t)gi * Nn + gj] = v;
      }
    }
  }
}

extern "C" void kernel_launch(void* const* d_in, const int* in_sizes, int n_in,
                              void* d_out, int out_size, void* d_ws, size_t ws_size,
                              hipStream_t stream) {
  const float* x = (const float*)d_in[0];  // [N,D]
  const float* w = (const float*)d_in[1];  // [D]
  const int* ei = (const int*)d_in[2];     // [2,E]
  const int* src = ei;
  const int* dstv = ei + Ee;
  float* out = (float*)d_out;

  // workspace (~71.4 MB)
  unsigned short* Mb = (unsigned short*)d_ws;                       // [4096][4096] bf16, tiled
  unsigned short* aext = Mb + (size_t)Nn * Nn;                      // [4096][1536] (12.6MB)
  unsigned short* bext = aext + (size_t)Nn * KEXT;                  // [4096][1536] (12.6MB)
  unsigned short* xb = bext + (size_t)Nn * KEXT;                    // [640][8192] (10.5MB)
  int2* ell = (int2*)(xb + (size_t)YC * XK);                        // WCAP*Nn (2MB)
  float* sq = (float*)(ell + (size_t)WCAP * Nn);                    // Nn
  float* dis = sq + Nn;                                             // Nn
  float* d2 = dis + Nn;                                             // Nn
  float* mu = d2 + Nn;                                              // Nn
  float* m1 = mu + Nn;                                              // Nn
  int* degi = (int*)(m1 + Nn);                                      // Nn -- zero block start
  int* degrow = degi + Nn;                                          // Nn
  int* slotcnt = degrow + Nn;                                       // Nn
  int* bincnt = slotcnt + Nn;                                       // WCAP+1 -- zero block end
  int* binbase = bincnt + (WCAP + 1);                               // WCAP+1
  int* perm = binbase + (WCAP + 1);                                 // Nn
  int* rnk = perm + Nn;                                             // Nn
  int* wsub = rnk + Nn;                                             // 64

  hipMemsetAsync(ell, 0, (size_t)WCAP * Nn * sizeof(int2), stream);
  hipMemsetAsync(degi, 0, sizeof(int) * (3 * Nn + (WCAP + 1)), stream);
  hipMemsetAsync(xb, 0, (size_t)YC * XK * sizeof(unsigned short), stream);

  k_sq<<<Nn, 256, 0, stream>>>(x, w, sq);
  k_count<<<Ee / 256, 256, 0, stream>>>(src, dstv, degi, degrow);
  k_dis<<<Nn / 256, 256, 0, stream>>>(degi, degrow, dis, d2);
  k_hist<<<1, 256, 0, stream>>>(degi, binbase);
  k_scatter<<<Nn / 256, 256, 0, stream>>>(degi, binbase, bincnt, perm, rnk);
  k_wsub<<<1, 64, 0, stream>>>(degi, perm, wsub);
  k_fill_ell<<<(Ee + Nn + 255) / 256, 256, 0, stream>>>(src, dstv, dis, rnk, slotcnt, ell);
  k_xpose<<<dim3(16, 128), 256, 0, stream>>>(x, xb);
  k_tail<<<Nn / 256, 256, 0, stream>>>(sq, xb);

  // M-pass: Mb = bf16(APPNP(I)), chunk-tiled output (full-line writes)
  k_appnp<<<Nn / CT8, TPB, Nn * sizeof(uint4), stream>>>(Mb, ell, perm, wsub);
  // Y = Mb * xb^T (hi+lo) ; epilogue builds aext/bext hi/lo splits + mu/m1
  k_ymm<<<dim3(YC / 128, Nn / 128), 256, 0, stream>>>(Mb, xb, w, aext, bext, mu, m1);
  // out = Mb Mb^T + Aext Bext^T + rank-2 ; diag *= d2  (8-wave 256^2, deep staging)
  k_mm2<<<256, 512, 131072, stream>>>(Mb, aext, bext, mu, m1, d2, out);
}

// Round 11
// 836.090 us; speedup vs baseline: 1.1019x; 1.1019x over previous
//
#include <hip/hip_runtime.h>
#include <stdint.h>

#define Nn 4096
#define Dd 512
#define Ee 65536
#define HOPS 10
#define TPB 512
#define RPT (Nn / TPB)  // 8 rows per thread
#define CT8 8           // packed bf16 columns per block (8 x bf16 = 16B LDS entry)
#define WCAP 64         // ELL slot capacity (max in-degree+1; Poisson(16) max ~38)
#define KEXT 1536       // hi/lo-split extension K: [Phi|Phi|Plo] x [Yhi|Ylo|Yhi]
#define YC 640          // padded col count of Y = [X(512)|u|1|pad...]
#define XK 8192         // xb row length: [hi(4096) | lo(4096)]
#define NTMM 88         // k_mm2 K-tiles: 64 (Mb, K=4096) + 24 (ext, K=1536)

typedef short bf16x8 __attribute__((ext_vector_type(8)));
typedef float f32x4 __attribute__((ext_vector_type(4)));

// ---------------- helpers ----------------
__device__ __forceinline__ unsigned short bf16r(float x) {  // RNE fp32->bf16
  unsigned int b = __float_as_uint(x);
  return (unsigned short)((b + 0x7FFFu + ((b >> 16) & 1u)) >> 16);
}
__device__ __forceinline__ unsigned int pkbf(float lo, float hi) {  // 2 cols -> 1 uint
  return (unsigned int)bf16r(lo) | ((unsigned int)bf16r(hi) << 16);
}
__device__ __forceinline__ float ubf(unsigned short h) {
  return __uint_as_float(((unsigned int)h) << 16);
}
__device__ __forceinline__ void gld16(const unsigned short* g, unsigned short* lds) {
  __builtin_amdgcn_global_load_lds(
      (const __attribute__((address_space(1))) unsigned int*)g,
      (__attribute__((address_space(3))) unsigned int*)lds, 16, 0, 0);
}

// ---------------- sq[i] = sum_d w_d * x[i,d]^2 ----------------
__global__ __launch_bounds__(256) void k_sq(const float* __restrict__ x,
                                            const float* __restrict__ w,
                                            float* __restrict__ sq) {
  int row = blockIdx.x;
  int tid = threadIdx.x;
  const float* xr = x + (size_t)row * Dd;
  float partial = 0.f;
  for (int d = tid; d < Dd; d += 256) {
    float xv = xr[d];
    partial += xv * xv * w[d];
  }
  for (int off = 32; off >= 1; off >>= 1) partial += __shfl_down(partial, off, 64);
  __shared__ float red[4];
  int wv = tid >> 6, ln = tid & 63;
  if (ln == 0) red[wv] = partial;
  __syncthreads();
  if (tid == 0) sq[row] = red[0] + red[1] + red[2] + red[3];
}

// ---------------- degree counting ----------------
__global__ void k_count(const int* __restrict__ src, const int* __restrict__ dst,
                        int* __restrict__ degi, int* __restrict__ degrow) {
  int e = blockIdx.x * blockDim.x + threadIdx.x;
  if (e < Ee) {
    atomicAdd(&degi[dst[e]], 1);
    atomicAdd(&degrow[src[e]], 1);
  }
}

// ---------------- dis = (deg_in+1)^-0.5 ; d2 = 1/(deg_row+1) ----------------
__global__ void k_dis(const int* __restrict__ degi, const int* __restrict__ degrow,
                      float* __restrict__ dis, float* __restrict__ d2) {
  int i = blockIdx.x * 256 + threadIdx.x;
  dis[i] = rsqrtf((float)(degi[i] + 1));
  d2[i] = 1.0f / ((float)degrow[i] + 1.0f);
}

// ---------------- histogram of (deg_in+1) + exclusive prefix -> binbase ----------------
__global__ void k_hist(const int* __restrict__ degi, int* __restrict__ binbase) {
  __shared__ int h[WCAP + 1];
  int t = threadIdx.x;
  if (t <= WCAP) h[t] = 0;
  __syncthreads();
  for (int i = t; i < Nn; i += 256) {
    int d = degi[i] + 1;
    if (d > WCAP) d = WCAP;
    atomicAdd(&h[d], 1);
  }
  __syncthreads();
  if (t == 0) {
    int run = 0;
    for (int b = 0; b <= WCAP; b++) { int c = h[b]; binbase[b] = run; run += c; }
  }
}

// ---------------- counting-sort scatter: perm (sorted pos -> row), rnk (row -> pos) ----------------
__global__ void k_scatter(const int* __restrict__ degi, const int* __restrict__ binbase,
                          int* __restrict__ bincnt, int* __restrict__ perm,
                          int* __restrict__ rnk) {
  int i = blockIdx.x * 256 + threadIdx.x;
  int d = degi[i] + 1;
  if (d > WCAP) d = WCAP;
  int pos = binbase[d] + atomicAdd(&bincnt[d], 1);
  perm[pos] = i;
  rnk[i] = pos;
}

// ---------------- per-(wave,chain) slot bounds ----------------
__global__ void k_wsub(const int* __restrict__ degi, const int* __restrict__ perm,
                       int* __restrict__ wsub) {
  int t = threadIdx.x;
  int d = degi[perm[t * 64 + 63]] + 1;
  wsub[t] = d > WCAP ? WCAP : d;
}

// ---------------- ELL fill (slot-major, sorted-position indexed) ----------------
__global__ void k_fill_ell(const int* __restrict__ src, const int* __restrict__ dst,
                           const float* __restrict__ dis, const int* __restrict__ rnk,
                           int* __restrict__ slot, int2* __restrict__ ell) {
  int i = blockIdx.x * blockDim.x + threadIdx.x;
  if (i < Ee) {
    int s = src[i], d = dst[i];
    int p = atomicAdd(&slot[d], 1);
    if (p < WCAP) ell[(size_t)p * Nn + rnk[d]] = make_int2(s, __float_as_int(dis[s] * dis[d]));
  } else if (i < Ee + Nn) {
    int v = i - Ee;
    int p = atomicAdd(&slot[v], 1);
    if (p < WCAP) ell[(size_t)p * Nn + rnk[v]] = make_int2(v, __float_as_int(dis[v] * dis[v]));
  }
}

// ---------------- xb[c][k] = bf16 hi/lo of X^T: rows c = feature cols, k = nodes ----------------
__global__ __launch_bounds__(256) void k_xpose(const float* __restrict__ x,
                                               unsigned short* __restrict__ xb) {
  __shared__ float tile[32][33];
  int cx = blockIdx.x, rx = blockIdx.y;
  int t = threadIdx.x, txc = t & 31, tyc = t >> 5;
#pragma unroll
  for (int i = 0; i < 4; i++) {
    int a = tyc + i * 8;
    tile[a][txc] = x[(size_t)(rx * 32 + a) * Dd + cx * 32 + txc];
  }
  __syncthreads();
#pragma unroll
  for (int i = 0; i < 4; i++) {
    int a = tyc + i * 8;
    int c = cx * 32 + a;
    float v = tile[txc][a];
    unsigned short hi = bf16r(v);
    xb[(size_t)c * XK + rx * 32 + txc] = hi;
    xb[(size_t)c * XK + Nn + rx * 32 + txc] = bf16r(v - ubf(hi));
  }
}

// ---------------- xb tail rows: u (=sq) at c=512, ones at c=513 ----------------
__global__ void k_tail(const float* __restrict__ sq, unsigned short* __restrict__ xb) {
  int r = blockIdx.x * 256 + threadIdx.x;
  float v = sq[r];
  unsigned short hi = bf16r(v);
  xb[(size_t)512 * XK + r] = hi;
  xb[(size_t)512 * XK + Nn + r] = bf16r(v - ubf(hi));
  xb[(size_t)513 * XK + r] = bf16r(1.0f);
  xb[(size_t)513 * XK + Nn + r] = 0;
}

// ---------------- fused 10-hop APPNP(I) -> Mb = bf16(M) row-major; h packed bf16x8 in LDS ----------------
__global__ __launch_bounds__(TPB, 4) void k_appnp(unsigned short* __restrict__ mb,
                                                  const int2* __restrict__ ell,
                                                  const int* __restrict__ perm,
                                                  const int* __restrict__ wsub) {
  extern __shared__ uint4 h4u[];  // Nn entries = 64 KB (8 bf16 cols packed)
  int j0 = blockIdx.x * CT8;
  int tid = threadIdx.x;
  int wv = tid >> 6, ln = tid & 63;
  int qb = wv * 512 + ln;

  // init h = identity columns j0..j0+7 (bf16(1.0) = 0x3F80 in the matching half-word)
#pragma unroll
  for (int rr = 0; rr < RPT; rr++) {
    int r = tid + rr * TPB;
    uint4 v = make_uint4(0u, 0u, 0u, 0u);
    int c = r - j0;
    if (c >= 0 && c < 8) {
      unsigned int one = (c & 1) ? 0x3F800000u : 0x00003F80u;
      if ((c >> 1) == 0) v.x = one;
      else if ((c >> 1) == 1) v.y = one;
      else if ((c >> 1) == 2) v.z = one;
      else v.w = one;
    }
    h4u[r] = v;
  }

  int ws[RPT];
#pragma unroll
  for (int rr = 0; rr < RPT; rr++)
    ws[rr] = __builtin_amdgcn_readfirstlane(wsub[wv * 8 + rr]);
  const int Wv = ws[RPT - 1];

  int rp[RPT], x0c[RPT];
#pragma unroll
  for (int rr = 0; rr < RPT; rr++) {
    rp[rr] = perm[qb + rr * 64];
    int c = rp[rr] - j0;
    x0c[rr] = (c >= 0 && c < 8) ? c : -1;
  }
  __syncthreads();

  for (int it = 0; it < HOPS; it++) {
    int2 cur[RPT];
#pragma unroll
    for (int rr = 0; rr < RPT; rr++) cur[rr] = ell[qb + rr * 64];
    float acc[RPT][8];
#pragma unroll
    for (int rr = 0; rr < RPT; rr++)
#pragma unroll
      for (int c = 0; c < 8; c++) acc[rr][c] = (x0c[rr] == c) ? 1.0f : 0.0f;
    for (int s = 0; s < Wv; s++) {
      int sn = s + 1;
      int2 nxt[RPT];
#pragma unroll
      for (int rr = 0; rr < RPT; rr++)
        if (sn < ws[rr]) nxt[rr] = ell[(size_t)sn * Nn + qb + rr * 64];
#pragma unroll
      for (int rr = 0; rr < RPT; rr++)
        if (s < ws[rr]) {
          float vv = __int_as_float(cur[rr].y);
          uint4 hu = h4u[cur[rr].x];
          acc[rr][0] = fmaf(vv, __uint_as_float(hu.x << 16), acc[rr][0]);
          acc[rr][1] = fmaf(vv, __uint_as_float(hu.x & 0xFFFF0000u), acc[rr][1]);
          acc[rr][2] = fmaf(vv, __uint_as_float(hu.y << 16), acc[rr][2]);
          acc[rr][3] = fmaf(vv, __uint_as_float(hu.y & 0xFFFF0000u), acc[rr][3]);
          acc[rr][4] = fmaf(vv, __uint_as_float(hu.z << 16), acc[rr][4]);
          acc[rr][5] = fmaf(vv, __uint_as_float(hu.z & 0xFFFF0000u), acc[rr][5]);
          acc[rr][6] = fmaf(vv, __uint_as_float(hu.w << 16), acc[rr][6]);
          acc[rr][7] = fmaf(vv, __uint_as_float(hu.w & 0xFFFF0000u), acc[rr][7]);
        }
#pragma unroll
      for (int rr = 0; rr < RPT; rr++)
        if (sn < ws[rr]) cur[rr] = nxt[rr];
    }
    __syncthreads();
#pragma unroll
    for (int rr = 0; rr < RPT; rr++) {
      uint4 v;
      v.x = pkbf(0.5f * acc[rr][0], 0.5f * acc[rr][1]);
      v.y = pkbf(0.5f * acc[rr][2], 0.5f * acc[rr][3]);
      v.z = pkbf(0.5f * acc[rr][4], 0.5f * acc[rr][5]);
      v.w = pkbf(0.5f * acc[rr][6], 0.5f * acc[rr][7]);
      h4u[rp[rr]] = v;
    }
    __syncthreads();
  }

#pragma unroll
  for (int rr = 0; rr < RPT; rr++) {
    int r = tid + rr * TPB;
    *(uint4*)&mb[(size_t)r * Nn + j0] = h4u[r];
  }
}

// ---------------- Y = Mb * xb^T, 64x128 tiles (320 blocks -> full GPU); epilogue -> ext ----------------
// Round-10 lesson: 160-block k_ymm left 96 CUs idle. 64(i)x128(j) tile, 4 waves of 32x64,
// As 8KB + Bs 16KB -> multiple blocks/CU. Same chunk-XOR swizzle (row bases stay mult-of-8).
__global__ __launch_bounds__(256) void k_ymm(const unsigned short* __restrict__ Mb,
                                             const unsigned short* __restrict__ xb,
                                             const float* __restrict__ wp,
                                             unsigned short* __restrict__ aext,
                                             unsigned short* __restrict__ bext,
                                             float* __restrict__ mu,
                                             float* __restrict__ m1) {
  __shared__ unsigned short As[64 * 64];
  __shared__ unsigned short Bs[128 * 64];
  int i0 = blockIdx.y * 64, j0 = blockIdx.x * 128;
  int tid = threadIdx.x, l = tid & 63, w = tid >> 6;
  int wr = w >> 1, wc = w & 1;
  int rsub = w * 8 + (l >> 3);
  int scg = ((l & 7) ^ (l >> 3)) * 8;
  f32x4 acc[2][4];
#pragma unroll
  for (int m = 0; m < 2; m++)
#pragma unroll
    for (int n = 0; n < 4; n++) acc[m][n] = (f32x4){0.f, 0.f, 0.f, 0.f};

  for (int seg = 0; seg < 2; seg++) {  // hi then lo half of xb K
    const unsigned short* Bsrc = xb + seg * Nn;
    for (int k0 = 0; k0 < Nn; k0 += 64) {
#pragma unroll
      for (int r = 0; r < 2; r++) {
        int row = r * 32 + rsub;
        gld16(Mb + (size_t)(i0 + row) * Nn + k0 + scg, As + (r * 32 + w * 8) * 64);
      }
#pragma unroll
      for (int r = 0; r < 4; r++) {
        int row = r * 32 + rsub;
        gld16(Bsrc + (size_t)(j0 + row) * XK + k0 + scg, Bs + (r * 32 + w * 8) * 64);
      }
      __syncthreads();
#pragma unroll
      for (int q = 0; q < 2; q++) {
        bf16x8 af[2], bg[4];
#pragma unroll
        for (int m = 0; m < 2; m++) {
          int ar = wr * 32 + m * 16 + (l & 15);
          af[m] = *(const bf16x8*)(As + ar * 64 + ((((l >> 4) + 4 * q) ^ (ar & 7)) * 8));
        }
#pragma unroll
        for (int n = 0; n < 4; n++) {
          int br = wc * 64 + n * 16 + (l & 15);
          bg[n] = *(const bf16x8*)(Bs + br * 64 + ((((l >> 4) + 4 * q) ^ (br & 7)) * 8));
        }
#pragma unroll
        for (int m = 0; m < 2; m++)
#pragma unroll
          for (int n = 0; n < 4; n++)
            acc[m][n] = __builtin_amdgcn_mfma_f32_16x16x32_bf16(af[m], bg[n], acc[m][n], 0, 0, 0);
      }
      __syncthreads();
    }
  }

#pragma unroll
  for (int m = 0; m < 2; m++) {
#pragma unroll
    for (int n = 0; n < 4; n++) {
#pragma unroll
      for (int q = 0; q < 4; q++) {
        int gi = i0 + wr * 32 + m * 16 + ((l >> 4) << 2) + q;
        int gj = j0 + wc * 64 + n * 16 + (l & 15);
        float y = acc[m][n][q];
        if (gj < 512) {
          unsigned short yhi = bf16r(y);
          unsigned short ylo = bf16r(y - ubf(yhi));
          float p = -2.f * wp[gj] * y;
          unsigned short phi = bf16r(p);
          unsigned short plo = bf16r(p - ubf(phi));
          bext[(size_t)gi * KEXT + gj] = yhi;
          bext[(size_t)gi * KEXT + 512 + gj] = ylo;
          bext[(size_t)gi * KEXT + 1024 + gj] = yhi;
          aext[(size_t)gi * KEXT + gj] = phi;
          aext[(size_t)gi * KEXT + 512 + gj] = phi;
          aext[(size_t)gi * KEXT + 1024 + gj] = plo;
        } else if (gj == 512) {
          mu[gi] = y;
        } else if (gj == 513) {
          m1[gi] = y;
        }
      }
    }
  }
}

// ---------------- 8-wave 256^2 GEMM (round-9 proven): out = Mb Mb^T + Aext Bext^T + rank2 ----
__global__ __launch_bounds__(512, 2) void k_mm2(const unsigned short* __restrict__ Mb,
                                                const unsigned short* __restrict__ Aext,
                                                const unsigned short* __restrict__ Bext,
                                                const float* __restrict__ mu,
                                                const float* __restrict__ m1,
                                                const float* __restrict__ d2,
                                                float* __restrict__ out) {
  extern __shared__ unsigned short sh[];  // [A0|A1|B0|B1], each 256*64 ushort = 32 KB
  int lid = blockIdx.x;
  int swz = (lid & 7) * 32 + (lid >> 3);  // 256 % 8 == 0 -> bijective XCD swizzle
  int i0 = (swz >> 4) * 256, j0 = (swz & 15) * 256;
  int tid = threadIdx.x, l = tid & 63, w = tid >> 6;
  int wr = w >> 2, wc = w & 3;
  int rsub = l >> 3;
  int scg = ((l & 7) ^ (l >> 3)) * 8;          // pre-swizzled source chunk (ushorts)
  int aRowBase = wr * 128 + wc * 32;           // wave's A staging rows
  int bRowBase = (wc >> 1) * 128 + (wr * 2 + (wc & 1)) * 32;  // wave's B staging rows

  f32x4 acc[8][4];
#pragma unroll
  for (int m = 0; m < 8; m++)
#pragma unroll
    for (int n = 0; n < 4; n++) acc[m][n] = (f32x4){0.f, 0.f, 0.f, 0.f};

  auto STG = [&](int g, int t, int b) {  // g 0-3: B stage ; g 4-7: A stage
    const unsigned short *pa, *pb;
    int lda, kk;
    if (t < 64) { pa = Mb; pb = Mb; lda = Nn; kk = t * 64; }
    else { pa = Aext; pb = Bext; lda = KEXT; kk = (t - 64) * 64; }
    if (g < 4) {
      int r = bRowBase + g * 8;
      gld16(pb + (size_t)(j0 + r + rsub) * lda + kk + scg, sh + 32768 + b * 16384 + r * 64);
    } else {
      int r = aRowBase + (g - 4) * 8;
      gld16(pa + (size_t)(i0 + r + rsub) * lda + kk + scg, sh + b * 16384 + r * 64);
    }
  };

  // prologue: stage tile 0 into buf 0, drain, barrier
#pragma unroll
  for (int g = 0; g < 8; g++) STG(g, 0, 0);
  asm volatile("s_waitcnt vmcnt(0)" ::: "memory");
  __builtin_amdgcn_s_barrier();

  for (int kt = 0; kt < NTMM; kt++) {
    int cur = kt & 1, nxtb = cur ^ 1;
    const unsigned short* Ac = sh + cur * 16384;
    const unsigned short* Bc = sh + 32768 + cur * 16384;
    bool pre = (kt + 1 < NTMM);
#pragma unroll
    for (int p = 0; p < 4; p++) {
      const int mh = p >> 1, nh = p & 1;
      bf16x8 af[4][2], bg[2][2];
#pragma unroll
      for (int m4 = 0; m4 < 4; m4++) {
        int ar = wr * 128 + (mh * 4 + m4) * 16 + (l & 15);
#pragma unroll
        for (int ks = 0; ks < 2; ks++) {
          int c = ks * 4 + (l >> 4);
          af[m4][ks] = *(const bf16x8*)(Ac + ar * 64 + ((c ^ (ar & 7)) * 8));
        }
      }
#pragma unroll
      for (int n2 = 0; n2 < 2; n2++) {
        int br = wc * 64 + (nh * 2 + n2) * 16 + (l & 15);
#pragma unroll
        for (int ks = 0; ks < 2; ks++) {
          int c = ks * 4 + (l >> 4);
          bg[n2][ks] = *(const bf16x8*)(Bc + br * 64 + ((c ^ (br & 7)) * 8));
        }
      }
      if (pre) {
        if (p == 0) { STG(0, kt + 1, nxtb); STG(1, kt + 1, nxtb); STG(2, kt + 1, nxtb); }
        else if (p == 1) { STG(3, kt + 1, nxtb); STG(4, kt + 1, nxtb); STG(5, kt + 1, nxtb); }
        else if (p == 2) { STG(6, kt + 1, nxtb); STG(7, kt + 1, nxtb); }
      }
      if (p == 3) asm volatile("s_waitcnt vmcnt(0)" ::: "memory");
      __builtin_amdgcn_s_barrier();
      __builtin_amdgcn_s_setprio(1);
#pragma unroll
      for (int m4 = 0; m4 < 4; m4++)
#pragma unroll
        for (int n2 = 0; n2 < 2; n2++)
#pragma unroll
          for (int ks = 0; ks < 2; ks++)
            acc[mh * 4 + m4][nh * 2 + n2] = __builtin_amdgcn_mfma_f32_16x16x32_bf16(
                af[m4][ks], bg[n2][ks], acc[mh * 4 + m4][nh * 2 + n2], 0, 0, 0);
      __builtin_amdgcn_s_setprio(0);
      __builtin_amdgcn_s_barrier();
    }
  }

#pragma unroll
  for (int m = 0; m < 8; m++) {
#pragma unroll
    for (int n = 0; n < 4; n++) {
#pragma unroll
      for (int q = 0; q < 4; q++) {
        int gi = i0 + wr * 128 + m * 16 + ((l >> 4) << 2) + q;
        int gj = j0 + wc * 64 + n * 16 + (l & 15);
        float v = acc[m][n][q] + mu[gi] * m1[gj] + m1[gi] * mu[gj];
        if (gi == gj) v *= d2[gi];
        out[(size_t)gi * Nn + gj] = v;
      }
    }
  }
}

extern "C" void kernel_launch(void* const* d_in, const int* in_sizes, int n_in,
                              void* d_out, int out_size, void* d_ws, size_t ws_size,
                              hipStream_t stream) {
  const float* x = (const float*)d_in[0];  // [N,D]
  const float* w = (const float*)d_in[1];  // [D]
  const int* ei = (const int*)d_in[2];     // [2,E]
  const int* src = ei;
  const int* dstv = ei + Ee;
  float* out = (float*)d_out;

  // workspace (~71.4 MB)
  unsigned short* Mb = (unsigned short*)d_ws;                       // [4096][4096] bf16 (33.5MB)
  unsigned short* aext = Mb + (size_t)Nn * Nn;                      // [4096][1536] (12.6MB)
  unsigned short* bext = aext + (size_t)Nn * KEXT;                  // [4096][1536] (12.6MB)
  unsigned short* xb = bext + (size_t)Nn * KEXT;                    // [640][8192] (10.5MB)
  int2* ell = (int2*)(xb + (size_t)YC * XK);                        // WCAP*Nn (2MB)
  float* sq = (float*)(ell + (size_t)WCAP * Nn);                    // Nn
  float* dis = sq + Nn;                                             // Nn
  float* d2 = dis + Nn;                                             // Nn
  float* mu = d2 + Nn;                                              // Nn
  float* m1 = mu + Nn;                                              // Nn
  int* degi = (int*)(m1 + Nn);                                      // Nn -- zero block start
  int* degrow = degi + Nn;                                          // Nn
  int* slotcnt = degrow + Nn;                                       // Nn
  int* bincnt = slotcnt + Nn;                                       // WCAP+1 -- zero block end
  int* binbase = bincnt + (WCAP + 1);                               // WCAP+1
  int* perm = binbase + (WCAP + 1);                                 // Nn
  int* rnk = perm + Nn;                                             // Nn
  int* wsub = rnk + Nn;                                             // 64

  hipMemsetAsync(ell, 0, (size_t)WCAP * Nn * sizeof(int2), stream);
  hipMemsetAsync(degi, 0, sizeof(int) * (3 * Nn + (WCAP + 1)), stream);
  hipMemsetAsync(xb, 0, (size_t)YC * XK * sizeof(unsigned short), stream);

  k_sq<<<Nn, 256, 0, stream>>>(x, w, sq);
  k_count<<<Ee / 256, 256, 0, stream>>>(src, dstv, degi, degrow);
  k_dis<<<Nn / 256, 256, 0, stream>>>(degi, degrow, dis, d2);
  k_hist<<<1, 256, 0, stream>>>(degi, binbase);
  k_scatter<<<Nn / 256, 256, 0, stream>>>(degi, binbase, bincnt, perm, rnk);
  k_wsub<<<1, 64, 0, stream>>>(degi, perm, wsub);
  k_fill_ell<<<(Ee + Nn + 255) / 256, 256, 0, stream>>>(src, dstv, dis, rnk, slotcnt, ell);
  k_xpose<<<dim3(16, 128), 256, 0, stream>>>(x, xb);
  k_tail<<<Nn / 256, 256, 0, stream>>>(sq, xb);

  // M-pass: Mb = bf16(APPNP(I)), 8 packed bf16 columns per block (row-major output)
  k_appnp<<<Nn / CT8, TPB, Nn * sizeof(uint4), stream>>>(Mb, ell, perm, wsub);
  // Y = Mb * xb^T (hi+lo) ; 64x128 tiles, 320 blocks (occupancy fix)
  k_ymm<<<dim3(YC / 128, Nn / 64), 256, 0, stream>>>(Mb, xb, w, aext, bext, mu, m1);
  // out = Mb Mb^T + Aext Bext^T + rank-2 ; diag *= d2  (8-wave 256^2, round-9 staging)
  k_mm2<<<256, 512, 131072, stream>>>(Mb, aext, bext, mu, m1, d2, out);
}